// Round 14
// baseline (461.418 us; speedup 1.0000x reference)
//
#include <hip/hip_runtime.h>

typedef unsigned short u16;
using f32x4  = __attribute__((ext_vector_type(4))) float;
using f32x16 = __attribute__((ext_vector_type(16))) float;
using s16x8  = __attribute__((ext_vector_type(8))) short;

// ---- helpers ---------------------------------------------------------------
static __device__ __forceinline__ u16 f2b(float f) {
  unsigned int u = __builtin_bit_cast(unsigned int, f);
  u = (u + 0x7fffu + ((u >> 16) & 1u)) >> 16;   // RNE, finite inputs only
  return (u16)u;
}
static __device__ __forceinline__ unsigned int cvtpk(float lo, float hi) {
  unsigned int r;
  asm("v_cvt_pk_bf16_f32 %0, %1, %2" : "=v"(r) : "v"(lo), "v"(hi));
  return r;
}
static __device__ __forceinline__ void gload16(const void* g, void* l) {
  __builtin_amdgcn_global_load_lds(
      (const __attribute__((address_space(1))) void*)g,
      (__attribute__((address_space(3))) void*)l, 16, 0, 0);
}

// ---- shared transpose-convert tile body (NT = block size) ------------------
template<int NT>
static __device__ __forceinline__ void transpose_tile(
    const float* __restrict__ W, u16* __restrict__ Wt, int K, int N,
    int n0, int k0, int t, u16 (*tile)[72])
{
  #pragma unroll
  for (int i = 0; i < 1024 / NT; ++i) {
    int idx = i * NT + t;
    int r = idx >> 4;
    int c = (idx & 15) << 2;
    float4 v = make_float4(0.f, 0.f, 0.f, 0.f);
    if (n0 + c < N) v = *(const float4*)(W + (size_t)(k0 + r) * N + n0 + c);
    tile[r][c + 0] = f2b(v.x);
    tile[r][c + 1] = f2b(v.y);
    tile[r][c + 2] = f2b(v.z);
    tile[r][c + 3] = f2b(v.w);
  }
  __syncthreads();
  #pragma unroll
  for (int i = 0; i < 512 / NT; ++i) {
    int idx = i * NT + t;
    int rn = idx >> 3;
    int c8 = (idx & 7) << 3;
    __align__(16) u16 tmp[8];
    #pragma unroll
    for (int j = 0; j < 8; ++j) tmp[j] = tile[c8 + j][rn];
    *(uint4*)(Wt + (size_t)(n0 + rn) * K + k0 + c8) = *(const uint4*)tmp;
  }
}

// ---- merged preprocessing: hidden->bf16 + Wqkv transpose-convert -----------
__global__ __launch_bounds__(256) void prep_kernel(
    const float* __restrict__ hidden, u16* __restrict__ A1,
    const float* __restrict__ Wqkv, u16* __restrict__ Wt)
{
  __shared__ u16 tile[64][72];
  const int bid = blockIdx.x, t = threadIdx.x;
  if (bid < 4544) {
    int i = bid * 256 + t;
    float4 a = *(const float4*)(hidden + (size_t)i * 8);
    float4 b = *(const float4*)(hidden + (size_t)i * 8 + 4);
    __align__(16) u16 tmp[8] = {f2b(a.x), f2b(a.y), f2b(a.z), f2b(a.w),
                                f2b(b.x), f2b(b.y), f2b(b.z), f2b(b.w)};
    *(uint4*)(A1 + (size_t)i * 8) = *(const uint4*)tmp;
  } else {
    int tb = bid - 4544;                  // 74 x 71 tiles
    int n0 = (tb % 74) * 64, k0 = (tb / 74) * 64;
    transpose_tile<256>(Wqkv, Wt, 4544, 4672, n0, k0, t, tile);
  }
}

// ---- GEMM: C = A * B^T (A bf16 [M][K], B bf16 [Npad][K]) -------------------
// r10 proven loop: 128x128, 4 waves, BK=32, 32 KB double-buffer, depth-1.5
// pipeline with counted vmcnt(4), both-sides XOR swizzle.
// SPLIT=1: block-level split-K. Grid = 2*half; bid<half -> ks=0 (K rows
// [0,KLEN)), else ks=1 ([KLEN,2*KLEN)). Partial fp32 -> C0/C1 (stride CW).
// SPLIT=0: MODE 0 plain fp32 C store; MODE 2 fused RoPE/QKV-split epilogue.
template<int MODE, int SPLIT>
__global__ __launch_bounds__(256) void gemm_bt(
    const u16* __restrict__ A, const u16* __restrict__ B,
    float* __restrict__ C0, float* __restrict__ C1,
    u16* __restrict__ qo, u16* __restrict__ ko, u16* __restrict__ vo,
    const int* __restrict__ pos,
    int M, int N, int K, int KLEN, int NBX, int CW)
{
  __shared__ __align__(16) u16 aLds[2][128 * 32];
  __shared__ __align__(16) u16 bLds[2][128 * 32];

  const int t = threadIdx.x, lane = t & 63, w = t >> 6;
  const int lr = lane & 15, lg = lane >> 4;
  const int wr = w >> 1, wc = w & 1;

  int bid = blockIdx.x, ks = 0;
  int half = SPLIT ? (gridDim.x >> 1) : gridDim.x;
  if (SPLIT && bid >= half) { ks = 1; bid -= half; }
  const int qq  = half >> 3;
  const int swz = (bid & 7) * qq + (bid >> 3);    // bijective: half % 8 == 0
  const int m0 = (swz / NBX) * 128, n0 = (swz % NBX) * 128;

  const u16* Ab = A + (size_t)ks * KLEN;
  const u16* Bb = B + (size_t)ks * KLEN;

  const int srow = lane >> 2;                        // 0..15
  const int ssl  = ((lane & 3) ^ ((lane >> 3) & 3)) << 3;  // swizzled src col

  f32x4 acc[4][4] = {};
  const int nk = KLEN >> 5;

#define STAGE(buf, tt) do {                                                   \
    size_t kq_ = (size_t)(tt) << 5;                                           \
    _Pragma("unroll")                                                         \
    for (int i_ = 0; i_ < 2; ++i_) {                                          \
      int row_ = i_ * 64 + w * 16 + srow;                                     \
      gload16(Ab + (size_t)(m0 + row_) * K + kq_ + ssl,                       \
              (char*)&aLds[buf][0] + i_ * 4096 + w * 1024);                   \
      gload16(Bb + (size_t)(n0 + row_) * K + kq_ + ssl,                       \
              (char*)&bLds[buf][0] + i_ * 4096 + w * 1024);                   \
    }                                                                         \
  } while (0)

  STAGE(0, 0);

  const int sl = (lg ^ ((lr >> 1) & 3)) << 3;        // swizzled read slot
  for (int kt = 0; kt < nk; ++kt) {
    const int cur = kt & 1;
    if (kt + 1 < nk) {
      STAGE(cur ^ 1, kt + 1);
      asm volatile("s_waitcnt vmcnt(4)" ::: "memory");
    } else {
      asm volatile("s_waitcnt vmcnt(0)" ::: "memory");
    }
    __builtin_amdgcn_s_barrier();
    __builtin_amdgcn_sched_barrier(0);
    const u16* ab = &aLds[cur][0];
    const u16* bb = &bLds[cur][0];
    s16x8 af[4], bf[4];
    #pragma unroll
    for (int m = 0; m < 4; ++m)
      af[m] = *(const s16x8*)(ab + (wr * 64 + m * 16 + lr) * 32 + sl);
    #pragma unroll
    for (int n = 0; n < 4; ++n)
      bf[n] = *(const s16x8*)(bb + (wc * 64 + n * 16 + lr) * 32 + sl);
    #pragma unroll
    for (int m = 0; m < 4; ++m)
      #pragma unroll
      for (int n = 0; n < 4; ++n)
        acc[m][n] = __builtin_amdgcn_mfma_f32_16x16x32_bf16(af[m], bf[n], acc[m][n], 0, 0, 0);
    __builtin_amdgcn_s_barrier();
  }
#undef STAGE

  if constexpr (SPLIT == 1) {
    float* Cp = ks ? C1 : C0;
    #pragma unroll
    for (int m = 0; m < 4; ++m) {
      int row = m0 + wr * 64 + m * 16 + lg * 4;
      #pragma unroll
      for (int n = 0; n < 4; ++n) {
        int col = n0 + wc * 64 + n * 16 + lr;
        if (col < N) {
          #pragma unroll
          for (int r = 0; r < 4; ++r)
            Cp[(size_t)(row + r) * CW + col] = acc[m][n][r];
        }
      }
    }
  } else if constexpr (MODE == 0) {
    #pragma unroll
    for (int m = 0; m < 4; ++m) {
      int row = m0 + wr * 64 + m * 16 + lg * 4;
      #pragma unroll
      for (int n = 0; n < 4; ++n) {
        int col = n0 + wc * 64 + n * 16 + lr;
        if (col < N) {
          #pragma unroll
          for (int r = 0; r < 4; ++r)
            C0[(size_t)(row + r) * N + col] = acc[m][n][r];
        }
      }
    }
  } else {
    const int h = (n0 + wc * 64) >> 6;
    if (h > 72) return;
    const float inv0 = exp2f(-0.41524101186092029f * (float)lr);
    const float inv1 = exp2f(-0.41524101186092029f * (float)(16 + lr));
    #pragma unroll
    for (int m = 0; m < 4; ++m) {
      #pragma unroll
      for (int r = 0; r < 4; ++r) {
        int row = m0 + wr * 64 + m * 16 + lg * 4 + r;
        int b = row >> 10, s = row & 1023;
        if (h == 72) {
          #pragma unroll
          for (int n = 0; n < 4; ++n) {
            int d = n * 16 + lr;
            vo[((size_t)b * 64 + d) * 1024 + s] = f2b(acc[m][n][r]);
          }
        } else {
          float p = (float)pos[s];
          float sn0, cs0, sn1, cs1;
          __sincosf(p * inv0, &sn0, &cs0);
          __sincosf(p * inv1, &sn1, &cs1);
          #pragma unroll
          for (int n = 0; n < 4; ++n) {
            float cs  = (n & 1) ? cs1 : cs0;
            float sn  = (n & 1) ? sn1 : sn0;
            float sgn = (n < 2) ? -1.f : 1.f;
            float val = acc[m][n][r] * cs + sgn * acc[m][n ^ 2][r] * sn;
            int d = n * 16 + lr;
            if (h < 71)
              qo[((size_t)(b * 71 + h) * 1024 + s) * 64 + d] = f2b(val);
            else
              ko[((size_t)b * 1024 + s) * 64 + d] = f2b(val);
          }
        }
      }
    }
  }
}

// ---- combine partials + RoPE/QKV-split (split-K path, GEMM1) ---------------
// grid (37, 2048), 128 threads: each thread one (row, col) of [2048][4736].
__global__ __launch_bounds__(128) void combine_rope(
    const float* __restrict__ P0, const float* __restrict__ P1,
    const int* __restrict__ pos,
    u16* __restrict__ qo, u16* __restrict__ ko, u16* __restrict__ vo)
{
  const int col = blockIdx.x * 128 + threadIdx.x;   // 0..4735
  const int row = blockIdx.y;                        // 0..2047
  const int h = col >> 6, d = col & 63;
  if (h >= 73) return;                               // padded cols
  const int b = row >> 10, s = row & 1023;
  const size_t idx = (size_t)row * 4736 + col;
  const float v0 = P0[idx] + P1[idx];
  if (h == 72) {                                     // V: transposed, no rope
    vo[((size_t)b * 64 + d) * 1024 + s] = f2b(v0);
    return;
  }
  const size_t idxp = (size_t)row * 4736 + (col ^ 32);
  const float vp = P0[idxp] + P1[idxp];
  const float p = (float)pos[s];
  const float inv = exp2f(-0.41524101186092029f * (float)(d & 31));
  float sn, cs;
  __sincosf(p * inv, &sn, &cs);
  const float sgn = (d < 32) ? -1.f : 1.f;
  const float val = v0 * cs + sgn * vp * sn;
  if (h < 71)
    qo[((size_t)(b * 71 + h) * 1024 + s) * 64 + d] = f2b(val);
  else
    ko[((size_t)b * 1024 + s) * 64 + d] = f2b(val);
}

// ---- combine partials (split-K path, GEMM2): out += P ----------------------
__global__ __launch_bounds__(256) void combine_add(
    float* __restrict__ out, const float* __restrict__ P)
{
  size_t i = (size_t)blockIdx.x * 256 + threadIdx.x;   // n4 = 2326528 exact
  float4 a = ((const float4*)out)[i];
  float4 b = ((const float4*)P)[i];
  a.x += b.x; a.y += b.y; a.z += b.z; a.w += b.w;
  ((float4*)out)[i] = a;
}

// ---- attention (blocks 0..2271) + Wdense transpose (blocks 2272..) ---------
// r10 proven: 1 head/block, swapped-QK 32x32 MFMA, in-reg softmax, no LDS.
__global__ __launch_bounds__(128) void attn_plus(
    const u16* __restrict__ q, const u16* __restrict__ kx,
    const u16* __restrict__ vT, u16* __restrict__ attnO,
    const float* __restrict__ Wd, u16* __restrict__ Wt)
{
  __shared__ u16 tile[64][72];
  const int bid = blockIdx.x;
  if (bid >= 2272) {                        // 72 x 71 transpose tiles
    int tb = bid - 2272;
    int n0 = (tb % 72) * 64, k0 = (tb / 72) * 64;
    transpose_tile<128>(Wd, Wt, 4544, 4544, n0, k0, threadIdx.x, tile);
    return;
  }
  const int t = threadIdx.x, lane = t & 63, w = t >> 6;
  const int lq  = lane & 31;
  const int hi  = lane >> 5;
  const int hi4 = hi << 2;
  const int pair = bid & 15, h = (bid >> 4) % 71, b = bid / 1136;
  const int qt = w ? (31 - pair) : pair;
  const int q0 = qt * 32;

  const u16* qbase = q + ((size_t)(b * 71 + h) * 1024 + q0 + lq) * 64 + hi * 8;
  s16x8 qf[4];
  #pragma unroll
  for (int kt = 0; kt < 4; ++kt) qf[kt] = *(const s16x8*)(qbase + kt * 16);

  f32x16 o0 = {}, o1 = {};
  float m = -1e30f, l = 0.f;

  const u16* kbase  = kx + ((size_t)b * 1024 + lq) * 64 + hi * 8;
  const u16* vbase0 = vT + ((size_t)b * 64 + lq) * 1024 + hi * 8;
  const u16* vbase1 = vbase0 + 32 * 1024;

  for (int it = 0; it <= qt; ++it) {
    const int kv0 = it * 32;
    s16x8 kf[4];
    #pragma unroll
    for (int kt = 0; kt < 4; ++kt)
      kf[kt] = *(const s16x8*)(kbase + (size_t)kv0 * 64 + kt * 16);
    s16x8 v00 = *(const s16x8*)(vbase0 + kv0);
    s16x8 v01 = *(const s16x8*)(vbase0 + kv0 + 16);
    s16x8 v10 = *(const s16x8*)(vbase1 + kv0);
    s16x8 v11 = *(const s16x8*)(vbase1 + kv0 + 16);

    f32x16 sa = {}, sb = {};
    sa = __builtin_amdgcn_mfma_f32_32x32x16_bf16(kf[0], qf[0], sa, 0, 0, 0);
    sb = __builtin_amdgcn_mfma_f32_32x32x16_bf16(kf[1], qf[1], sb, 0, 0, 0);
    sa = __builtin_amdgcn_mfma_f32_32x32x16_bf16(kf[2], qf[2], sa, 0, 0, 0);
    sb = __builtin_amdgcn_mfma_f32_32x32x16_bf16(kf[3], qf[3], sb, 0, 0, 0);

    float s[16];
    float pmax = -1e30f;
    if (it == qt) {
      #pragma unroll
      for (int r = 0; r < 16; ++r) {
        int R = (r & 3) + ((r >> 2) << 3) + hi4;
        s[r] = (R > lq) ? -1e30f : (sa[r] + sb[r]) * 0.125f;
        pmax = fmaxf(pmax, s[r]);
      }
    } else {
      #pragma unroll
      for (int r = 0; r < 16; ++r) {
        s[r] = (sa[r] + sb[r]) * 0.125f;
        pmax = fmaxf(pmax, s[r]);
      }
    }
    pmax = fmaxf(pmax, __shfl_xor(pmax, 32));

    if (!__all(pmax <= m + 8.f)) {
      float mn = fmaxf(m, pmax);
      float corr = __expf(m - mn);
      m = mn;
      l *= corr;
      #pragma unroll
      for (int r = 0; r < 16; ++r) {
        float c2 = __shfl(corr, (r & 3) + ((r >> 2) << 3) + hi4);
        o0[r] *= c2; o1[r] *= c2;
      }
    }

    float p[16], sum = 0.f;
    #pragma unroll
    for (int r = 0; r < 16; ++r) { p[r] = __expf(s[r] - m); sum += p[r]; }
    sum += __shfl_xor(sum, 32);
    l += sum;

    unsigned int a0 = cvtpk(p[0], p[1]),   a1 = cvtpk(p[2], p[3]);
    unsigned int b0 = cvtpk(p[4], p[5]),   b1 = cvtpk(p[6], p[7]);
    asm("v_permlane32_swap_b32 %0, %1" : "+v"(a0), "+v"(b0));
    asm("v_permlane32_swap_b32 %0, %1" : "+v"(a1), "+v"(b1));
    unsigned int c0 = cvtpk(p[8], p[9]),   c1 = cvtpk(p[10], p[11]);
    unsigned int d0 = cvtpk(p[12], p[13]), d1 = cvtpk(p[14], p[15]);
    asm("v_permlane32_swap_b32 %0, %1" : "+v"(c0), "+v"(d0));
    asm("v_permlane32_swap_b32 %0, %1" : "+v"(c1), "+v"(d1));
    union { unsigned int wd[4]; s16x8 v; } palo, pahi;
    palo.wd[0] = a0; palo.wd[1] = a1; palo.wd[2] = b0; palo.wd[3] = b1;
    pahi.wd[0] = c0; pahi.wd[1] = c1; pahi.wd[2] = d0; pahi.wd[3] = d1;

    o0 = __builtin_amdgcn_mfma_f32_32x32x16_bf16(palo.v, v00, o0, 0, 0, 0);
    o0 = __builtin_amdgcn_mfma_f32_32x32x16_bf16(pahi.v, v01, o0, 0, 0, 0);
    o1 = __builtin_amdgcn_mfma_f32_32x32x16_bf16(palo.v, v10, o1, 0, 0, 0);
    o1 = __builtin_amdgcn_mfma_f32_32x32x16_bf16(pahi.v, v11, o1, 0, 0, 0);
  }

  float linv = 1.f / l;
  #pragma unroll
  for (int r = 0; r < 16; ++r) {
    int R = (r & 3) + ((r >> 2) << 3) + hi4;
    float c2 = __shfl(linv, R);
    size_t base = ((size_t)(b * 1024 + q0 + R) * 71 + h) * 64;
    attnO[base + lq]      = f2b(o0[r] * c2);
    attnO[base + 32 + lq] = f2b(o1[r] * c2);
  }
}

// ---- launcher --------------------------------------------------------------
extern "C" void kernel_launch(void* const* d_in, const int* in_sizes, int n_in,
                              void* d_out, int out_size, void* d_ws, size_t ws_size,
                              hipStream_t stream) {
  const float* hidden = (const float*)d_in[0];   // [2,1024,4544]
  const float* Wqkv   = (const float*)d_in[1];   // [4544,4672]
  const float* Wdense = (const float*)d_in[2];   // [4544,4544]
  const int*   pos    = (const int*)d_in[4];     // [1,1024]
  float* out = (float*)d_out;                    // [2,1024,4544] fp32

  char* wsp = (char*)d_ws;
  // layout: Wt 43,040,768 | A1 18,612,224 | q 18,612,224 | k 262,144 |
  //         v 262,144 | P0 38,797,312 | P1 38,797,312  = 158,384,128 total
  u16* Wt    = (u16*)(wsp);
  u16* A1    = (u16*)(wsp + 43040768);
  u16* qws   = (u16*)(wsp + 43040768 + 18612224);
  u16* kws   = (u16*)(wsp + 43040768 + 18612224 + 18612224);
  u16* vws   = (u16*)(wsp + 43040768 + 18612224 + 18612224 + 262144);
  float* P0  = (float*)(wsp + 80789504);
  float* P1  = (float*)(wsp + 80789504 + 38797312);
  u16* attnw = A1;     // A1 dead after GEMM1 reads it

  const bool split = ws_size >= 158384128ull;

  // 1) merged: hidden->bf16 (4544 blocks) + Wqkv^T->bf16 (5254 blocks)
  prep_kernel<<<4544 + 5254, 256, 0, stream>>>(hidden, A1, Wqkv, Wt);

  if (split) {
    // 2) QKV GEMM, block split-K2 -> fp32 partials (1184 blocks)
    gemm_bt<0, 1><<<1184, 256, 0, stream>>>(A1, Wt, P0, P1,
        nullptr, nullptr, nullptr, nullptr, 2048, 4736, 4544, 2272, 37, 4736);
    // 2b) combine + RoPE/QKV-split
    combine_rope<<<dim3(37, 2048), 128, 0, stream>>>(P0, P1, pos, qws, kws, vws);
  } else {
    gemm_bt<2, 0><<<592, 256, 0, stream>>>(A1, Wt, nullptr, nullptr,
        qws, kws, vws, pos, 2048, 4672, 4544, 4544, 37, 0);
  }

  // 3) merged: attention (2272) + Wdense^T->bf16 (5112)
  attn_plus<<<2272 + 5112, 128, 0, stream>>>(qws, kws, vws, attnw, Wdense, Wt);

  if (split) {
    // 4) dense GEMM, split-K2: ks=0 -> out, ks=1 -> P0 (reused)
    gemm_bt<0, 1><<<1152, 256, 0, stream>>>(attnw, Wt, out, P0,
        nullptr, nullptr, nullptr, nullptr, 2048, 4544, 4544, 2272, 36, 4544);
    // 4b) out += P0
    combine_add<<<9088, 256, 0, stream>>>(out, P0);
  } else {
    gemm_bt<0, 0><<<576, 256, 0, stream>>>(attnw, Wt, out, nullptr,
        nullptr, nullptr, nullptr, nullptr, 2048, 4544, 4544, 4544, 36, 0);
  }
}

// Round 15
// 382.854 us; speedup vs baseline: 1.2052x; 1.2052x over previous
//
#include <hip/hip_runtime.h>

typedef unsigned short u16;
using f32x4  = __attribute__((ext_vector_type(4))) float;
using f32x16 = __attribute__((ext_vector_type(16))) float;
using s16x8  = __attribute__((ext_vector_type(8))) short;

// ---- helpers ---------------------------------------------------------------
static __device__ __forceinline__ u16 f2b(float f) {
  unsigned int u = __builtin_bit_cast(unsigned int, f);
  u = (u + 0x7fffu + ((u >> 16) & 1u)) >> 16;   // RNE, finite inputs only
  return (u16)u;
}
static __device__ __forceinline__ unsigned int cvtpk(float lo, float hi) {
  unsigned int r;
  asm("v_cvt_pk_bf16_f32 %0, %1, %2" : "=v"(r) : "v"(lo), "v"(hi));
  return r;
}
static __device__ __forceinline__ void gload16(const void* g, void* l) {
  __builtin_amdgcn_global_load_lds(
      (const __attribute__((address_space(1))) void*)g,
      (__attribute__((address_space(3))) void*)l, 16, 0, 0);
}

// ---- shared transpose-convert tile body (NT = block size) ------------------
template<int NT>
static __device__ __forceinline__ void transpose_tile(
    const float* __restrict__ W, u16* __restrict__ Wt, int K, int N,
    int n0, int k0, int t, u16 (*tile)[72])
{
  #pragma unroll
  for (int i = 0; i < 1024 / NT; ++i) {
    int idx = i * NT + t;
    int r = idx >> 4;
    int c = (idx & 15) << 2;
    float4 v = make_float4(0.f, 0.f, 0.f, 0.f);
    if (n0 + c < N) v = *(const float4*)(W + (size_t)(k0 + r) * N + n0 + c);
    tile[r][c + 0] = f2b(v.x);
    tile[r][c + 1] = f2b(v.y);
    tile[r][c + 2] = f2b(v.z);
    tile[r][c + 3] = f2b(v.w);
  }
  __syncthreads();
  #pragma unroll
  for (int i = 0; i < 512 / NT; ++i) {
    int idx = i * NT + t;
    int rn = idx >> 3;
    int c8 = (idx & 7) << 3;
    __align__(16) u16 tmp[8];
    #pragma unroll
    for (int j = 0; j < 8; ++j) tmp[j] = tile[c8 + j][rn];
    *(uint4*)(Wt + (size_t)(n0 + rn) * K + k0 + c8) = *(const uint4*)tmp;
  }
}

// ---- merged preprocessing: Wqkv transpose tiles FIRST (long pole), then
//      hidden->bf16 conv blocks (short, backfill the tail) ------------------
__global__ __launch_bounds__(256) void prep_kernel(
    const float* __restrict__ hidden, u16* __restrict__ A1,
    const float* __restrict__ Wqkv, u16* __restrict__ Wt)
{
  __shared__ u16 tile[64][72];
  const int bid = blockIdx.x, t = threadIdx.x;
  if (bid < 5254) {                       // 74 x 71 transpose tiles first
    int n0 = (bid % 74) * 64, k0 = (bid / 74) * 64;
    transpose_tile<256>(Wqkv, Wt, 4544, 4672, n0, k0, t, tile);
  } else {                                // conv: 4544*256*8 == 2048*4544 exact
    int i = (bid - 5254) * 256 + t;
    float4 a = *(const float4*)(hidden + (size_t)i * 8);
    float4 b = *(const float4*)(hidden + (size_t)i * 8 + 4);
    __align__(16) u16 tmp[8] = {f2b(a.x), f2b(a.y), f2b(a.z), f2b(a.w),
                                f2b(b.x), f2b(b.y), f2b(b.z), f2b(b.w)};
    *(uint4*)(A1 + (size_t)i * 8) = *(const uint4*)tmp;
  }
}

// ---- GEMM: C[M,N] = A[M,K] * B^T  (A bf16 [M][K], B bf16 [Npad][K]) --------
// r10 proven config: 128x128, 4 waves, BK=32, double-buffered 32 KB LDS,
// depth-1.5 pipeline: STAGE(t+1) -> vmcnt(4) -> barrier -> ds_read+MFMA ->
// barrier. Counted wait never drains in-loop. 64B-row XOR swizzle both-sides.
// MODE 0: plain fp32 C store. MODE 2: fused RoPE/QKV-split epilogue.
template<int MODE>
__global__ __launch_bounds__(256) void gemm_bt(
    const u16* __restrict__ A, const u16* __restrict__ B,
    float* __restrict__ Cptr,
    u16* __restrict__ qo, u16* __restrict__ ko, u16* __restrict__ vo,
    const int* __restrict__ pos,
    int M, int N, int K, int NBX)
{
  __shared__ __align__(16) u16 aLds[2][128 * 32];
  __shared__ __align__(16) u16 bLds[2][128 * 32];

  const int t = threadIdx.x, lane = t & 63, w = t >> 6;
  const int lr = lane & 15, lg = lane >> 4;
  const int wr = w >> 1, wc = w & 1;

  const int bid = blockIdx.x;
  const int qq  = gridDim.x >> 3;
  const int swz = (bid & 7) * qq + (bid >> 3);    // bijective: grid % 8 == 0
  const int m0 = (swz / NBX) * 128, n0 = (swz % NBX) * 128;

  const int srow = lane >> 2;                        // 0..15
  const int ssl  = ((lane & 3) ^ ((lane >> 3) & 3)) << 3;  // swizzled src col (u16)

  f32x4 acc[4][4] = {};
  const int nk = K >> 5;                 // 4544/32 = 142

#define STAGE(buf, tt) do {                                                   \
    size_t kq_ = (size_t)(tt) << 5;                                           \
    _Pragma("unroll")                                                         \
    for (int i_ = 0; i_ < 2; ++i_) {                                          \
      int row_ = i_ * 64 + w * 16 + srow;                                     \
      gload16(A + (size_t)(m0 + row_) * K + kq_ + ssl,                        \
              (char*)&aLds[buf][0] + i_ * 4096 + w * 1024);                   \
      gload16(B + (size_t)(n0 + row_) * K + kq_ + ssl,                        \
              (char*)&bLds[buf][0] + i_ * 4096 + w * 1024);                   \
    }                                                                         \
  } while (0)

  // prologue: tile 0 in flight
  STAGE(0, 0);

  const int sl = (lg ^ ((lr >> 1) & 3)) << 3;        // swizzled read slot (u16)
  for (int kt = 0; kt < nk; ++kt) {
    const int cur = kt & 1;
    if (kt + 1 < nk) {
      STAGE(cur ^ 1, kt + 1);                         // issue early (pre-wait)
      asm volatile("s_waitcnt vmcnt(4)" ::: "memory");   // tile kt landed
    } else {
      asm volatile("s_waitcnt vmcnt(0)" ::: "memory");
    }
    __builtin_amdgcn_s_barrier();          // all waves' tile-kt loads landed
    __builtin_amdgcn_sched_barrier(0);     // pin: no ds_read above barrier
    const u16* ab = &aLds[cur][0];
    const u16* bb = &bLds[cur][0];
    s16x8 af[4], bf[4];
    #pragma unroll
    for (int m = 0; m < 4; ++m)
      af[m] = *(const s16x8*)(ab + (wr * 64 + m * 16 + lr) * 32 + sl);
    #pragma unroll
    for (int n = 0; n < 4; ++n)
      bf[n] = *(const s16x8*)(bb + (wc * 64 + n * 16 + lr) * 32 + sl);
    #pragma unroll
    for (int m = 0; m < 4; ++m)
      #pragma unroll
      for (int n = 0; n < 4; ++n)
        acc[m][n] = __builtin_amdgcn_mfma_f32_16x16x32_bf16(af[m], bf[n], acc[m][n], 0, 0, 0);
    __builtin_amdgcn_s_barrier();          // reads(kt) done before STAGE(kt+2)
  }
#undef STAGE

  if constexpr (MODE == 0) {
    #pragma unroll
    for (int m = 0; m < 4; ++m) {
      int row = m0 + wr * 64 + m * 16 + lg * 4;
      #pragma unroll
      for (int n = 0; n < 4; ++n) {
        int col = n0 + wc * 64 + n * 16 + lr;
        if (col < N) {
          #pragma unroll
          for (int r = 0; r < 4; ++r)
            Cptr[(size_t)(row + r) * N + col] = acc[m][n][r];
        }
      }
    }
  } else {
    const int h = (n0 + wc * 64) >> 6;       // head index for this wave
    if (h > 72) return;                       // zero-padded columns
    const float inv0 = exp2f(-0.41524101186092029f * (float)lr);
    const float inv1 = exp2f(-0.41524101186092029f * (float)(16 + lr));
    #pragma unroll
    for (int m = 0; m < 4; ++m) {
      #pragma unroll
      for (int r = 0; r < 4; ++r) {
        int row = m0 + wr * 64 + m * 16 + lg * 4 + r;
        int b = row >> 10, s = row & 1023;
        if (h == 72) {                        // V: no rope, transposed store
          #pragma unroll
          for (int n = 0; n < 4; ++n) {
            int d = n * 16 + lr;
            vo[((size_t)b * 64 + d) * 1024 + s] = f2b(acc[m][n][r]);
          }
        } else {                              // Q / K: rope in registers
          float p = (float)pos[s];
          float sn0, cs0, sn1, cs1;
          __sincosf(p * inv0, &sn0, &cs0);
          __sincosf(p * inv1, &sn1, &cs1);
          #pragma unroll
          for (int n = 0; n < 4; ++n) {
            float cs  = (n & 1) ? cs1 : cs0;
            float sn  = (n & 1) ? sn1 : sn0;
            float sgn = (n < 2) ? -1.f : 1.f;
            float val = acc[m][n][r] * cs + sgn * acc[m][n ^ 2][r] * sn;
            int d = n * 16 + lr;
            if (h < 71)
              qo[((size_t)(b * 71 + h) * 1024 + s) * 64 + d] = f2b(val);
            else
              ko[((size_t)b * 1024 + s) * 64 + d] = f2b(val);
          }
        }
      }
    }
  }
}

// ---- attention (blocks 0..2271) + Wdense transpose (blocks 2272..) ---------
// attn: swapped-QK 32x32 MFMA, in-reg softmax, no LDS/barriers; 2 waves/block.
__global__ __launch_bounds__(128) void attn_plus(
    const u16* __restrict__ q, const u16* __restrict__ kx,
    const u16* __restrict__ vT, u16* __restrict__ attnO,
    const float* __restrict__ Wd, u16* __restrict__ Wt)
{
  __shared__ u16 tile[64][72];
  const int bid = blockIdx.x;
  if (bid >= 2272) {                        // 72 x 71 transpose tiles
    int tb = bid - 2272;
    int n0 = (tb % 72) * 64, k0 = (tb / 72) * 64;
    transpose_tile<128>(Wd, Wt, 4544, 4544, n0, k0, threadIdx.x, tile);
    return;
  }
  const int t = threadIdx.x, lane = t & 63, w = t >> 6;
  const int lq  = lane & 31;
  const int hi  = lane >> 5;
  const int hi4 = hi << 2;
  const int pair = bid & 15, h = (bid >> 4) % 71, b = bid / 1136;
  const int qt = w ? (31 - pair) : pair;
  const int q0 = qt * 32;

  const u16* qbase = q + ((size_t)(b * 71 + h) * 1024 + q0 + lq) * 64 + hi * 8;
  s16x8 qf[4];
  #pragma unroll
  for (int kt = 0; kt < 4; ++kt) qf[kt] = *(const s16x8*)(qbase + kt * 16);

  f32x16 o0 = {}, o1 = {};
  float m = -1e30f, l = 0.f;

  const u16* kbase  = kx + ((size_t)b * 1024 + lq) * 64 + hi * 8;
  const u16* vbase0 = vT + ((size_t)b * 64 + lq) * 1024 + hi * 8;
  const u16* vbase1 = vbase0 + 32 * 1024;

  for (int it = 0; it <= qt; ++it) {
    const int kv0 = it * 32;
    s16x8 kf[4];
    #pragma unroll
    for (int kt = 0; kt < 4; ++kt)
      kf[kt] = *(const s16x8*)(kbase + (size_t)kv0 * 64 + kt * 16);
    s16x8 v00 = *(const s16x8*)(vbase0 + kv0);
    s16x8 v01 = *(const s16x8*)(vbase0 + kv0 + 16);
    s16x8 v10 = *(const s16x8*)(vbase1 + kv0);
    s16x8 v11 = *(const s16x8*)(vbase1 + kv0 + 16);

    f32x16 sa = {}, sb = {};
    sa = __builtin_amdgcn_mfma_f32_32x32x16_bf16(kf[0], qf[0], sa, 0, 0, 0);
    sb = __builtin_amdgcn_mfma_f32_32x32x16_bf16(kf[1], qf[1], sb, 0, 0, 0);
    sa = __builtin_amdgcn_mfma_f32_32x32x16_bf16(kf[2], qf[2], sa, 0, 0, 0);
    sb = __builtin_amdgcn_mfma_f32_32x32x16_bf16(kf[3], qf[3], sb, 0, 0, 0);

    float s[16];
    float pmax = -1e30f;
    if (it == qt) {
      #pragma unroll
      for (int r = 0; r < 16; ++r) {
        int R = (r & 3) + ((r >> 2) << 3) + hi4;
        s[r] = (R > lq) ? -1e30f : (sa[r] + sb[r]) * 0.125f;
        pmax = fmaxf(pmax, s[r]);
      }
    } else {
      #pragma unroll
      for (int r = 0; r < 16; ++r) {
        s[r] = (sa[r] + sb[r]) * 0.125f;
        pmax = fmaxf(pmax, s[r]);
      }
    }
    pmax = fmaxf(pmax, __shfl_xor(pmax, 32));

    if (!__all(pmax <= m + 8.f)) {
      float mn = fmaxf(m, pmax);
      float corr = __expf(m - mn);
      m = mn;
      l *= corr;
      #pragma unroll
      for (int r = 0; r < 16; ++r) {
        float c2 = __shfl(corr, (r & 3) + ((r >> 2) << 3) + hi4);
        o0[r] *= c2; o1[r] *= c2;
      }
    }

    float p[16], sum = 0.f;
    #pragma unroll
    for (int r = 0; r < 16; ++r) { p[r] = __expf(s[r] - m); sum += p[r]; }
    sum += __shfl_xor(sum, 32);
    l += sum;

    unsigned int a0 = cvtpk(p[0], p[1]),   a1 = cvtpk(p[2], p[3]);
    unsigned int b0 = cvtpk(p[4], p[5]),   b1 = cvtpk(p[6], p[7]);
    asm("v_permlane32_swap_b32 %0, %1" : "+v"(a0), "+v"(b0));
    asm("v_permlane32_swap_b32 %0, %1" : "+v"(a1), "+v"(b1));
    unsigned int c0 = cvtpk(p[8], p[9]),   c1 = cvtpk(p[10], p[11]);
    unsigned int d0 = cvtpk(p[12], p[13]), d1 = cvtpk(p[14], p[15]);
    asm("v_permlane32_swap_b32 %0, %1" : "+v"(c0), "+v"(d0));
    asm("v_permlane32_swap_b32 %0, %1" : "+v"(c1), "+v"(d1));
    union { unsigned int wd[4]; s16x8 v; } palo, pahi;
    palo.wd[0] = a0; palo.wd[1] = a1; palo.wd[2] = b0; palo.wd[3] = b1;
    pahi.wd[0] = c0; pahi.wd[1] = c1; pahi.wd[2] = d0; pahi.wd[3] = d1;

    o0 = __builtin_amdgcn_mfma_f32_32x32x16_bf16(palo.v, v00, o0, 0, 0, 0);
    o0 = __builtin_amdgcn_mfma_f32_32x32x16_bf16(pahi.v, v01, o0, 0, 0, 0);
    o1 = __builtin_amdgcn_mfma_f32_32x32x16_bf16(palo.v, v10, o1, 0, 0, 0);
    o1 = __builtin_amdgcn_mfma_f32_32x32x16_bf16(pahi.v, v11, o1, 0, 0, 0);
  }

  float linv = 1.f / l;
  #pragma unroll
  for (int r = 0; r < 16; ++r) {
    int R = (r & 3) + ((r >> 2) << 3) + hi4;
    float c2 = __shfl(linv, R);
    size_t base = ((size_t)(b * 1024 + q0 + R) * 71 + h) * 64;
    attnO[base + lq]      = f2b(o0[r] * c2);
    attnO[base + 32 + lq] = f2b(o1[r] * c2);
  }
}

// ---- launcher --------------------------------------------------------------
extern "C" void kernel_launch(void* const* d_in, const int* in_sizes, int n_in,
                              void* d_out, int out_size, void* d_ws, size_t ws_size,
                              hipStream_t stream) {
  const float* hidden = (const float*)d_in[0];   // [2,1024,4544]
  const float* Wqkv   = (const float*)d_in[1];   // [4544,4672]
  const float* Wdense = (const float*)d_in[2];   // [4544,4544]
  const int*   pos    = (const int*)d_in[4];     // [1,1024]
  float* out = (float*)d_out;                    // [2,1024,4544] fp32

  char* wsp = (char*)d_ws;
  // buffer plan (82.0 MB total):
  //  Wt:   4736 x 4544 bf16 = 43,040,768   (Wqkv^T, then overwritten by Wdense^T)
  //  A1:   18,612,224  hidden bf16 -> (after GEMM1) reused as attn output
  //  q:    18,612,224
  //  k,vT: 262,144 each
  u16* Wt    = (u16*)(wsp);
  u16* A1    = (u16*)(wsp + 43040768);
  u16* qws   = (u16*)(wsp + 43040768 + 18612224);
  u16* kws   = (u16*)(wsp + 43040768 + 18612224 + 18612224);
  u16* vws   = (u16*)(wsp + 43040768 + 18612224 + 18612224 + 262144);
  u16* attnw = A1;     // A1 dead after GEMM1 reads it

  // 1) merged: Wqkv^T->bf16 (5254 blocks, first) + hidden->bf16 (4544 blocks)
  prep_kernel<<<5254 + 4544, 256, 0, stream>>>(hidden, A1, Wqkv, Wt);
  // 2) QKV GEMM (M=2048, Npad=4736, K=4544): 592 blocks (128x128, r10 config)
  gemm_bt<2><<<592, 256, 0, stream>>>(A1, Wt, nullptr, qws, kws, vws, pos,
                                      2048, 4672, 4544, 37);
  // 3) merged: attention (2272) + Wdense^T->bf16 (5112)
  attn_plus<<<2272 + 5112, 128, 0, stream>>>(qws, kws, vws, attnw, Wdense, Wt);
  // 4) out = attn @ W_dense (M=2048, Npad=4608, K=4544): 576 blocks
  gemm_bt<0><<<576, 256, 0, stream>>>(attnw, Wt, out, nullptr, nullptr, nullptr,
                                      nullptr, 2048, 4544, 4544, 36);
}

// Round 16
// 378.920 us; speedup vs baseline: 1.2177x; 1.0104x over previous
//
#include <hip/hip_runtime.h>

typedef unsigned short u16;
using f32x4  = __attribute__((ext_vector_type(4))) float;
using f32x16 = __attribute__((ext_vector_type(16))) float;
using s16x8  = __attribute__((ext_vector_type(8))) short;

// ---- helpers ---------------------------------------------------------------
static __device__ __forceinline__ u16 f2b(float f) {
  unsigned int u = __builtin_bit_cast(unsigned int, f);
  u = (u + 0x7fffu + ((u >> 16) & 1u)) >> 16;   // RNE, finite inputs only
  return (u16)u;
}
static __device__ __forceinline__ unsigned int cvtpk(float lo, float hi) {
  unsigned int r;
  asm("v_cvt_pk_bf16_f32 %0, %1, %2" : "=v"(r) : "v"(lo), "v"(hi));
  return r;
}
static __device__ __forceinline__ void gload16(const void* g, void* l) {
  __builtin_amdgcn_global_load_lds(
      (const __attribute__((address_space(1))) void*)g,
      (__attribute__((address_space(3))) void*)l, 16, 0, 0);
}

// ---- shared transpose-convert tile body (NT = block size) ------------------
template<int NT>
static __device__ __forceinline__ void transpose_tile(
    const float* __restrict__ W, u16* __restrict__ Wt, int K, int N,
    int n0, int k0, int t, u16 (*tile)[72])
{
  #pragma unroll
  for (int i = 0; i < 1024 / NT; ++i) {
    int idx = i * NT + t;
    int r = idx >> 4;
    int c = (idx & 15) << 2;
    float4 v = make_float4(0.f, 0.f, 0.f, 0.f);
    if (n0 + c < N) v = *(const float4*)(W + (size_t)(k0 + r) * N + n0 + c);
    tile[r][c + 0] = f2b(v.x);
    tile[r][c + 1] = f2b(v.y);
    tile[r][c + 2] = f2b(v.z);
    tile[r][c + 3] = f2b(v.w);
  }
  __syncthreads();
  #pragma unroll
  for (int i = 0; i < 512 / NT; ++i) {
    int idx = i * NT + t;
    int rn = idx >> 3;
    int c8 = (idx & 7) << 3;
    __align__(16) u16 tmp[8];
    #pragma unroll
    for (int j = 0; j < 8; ++j) tmp[j] = tile[c8 + j][rn];
    *(uint4*)(Wt + (size_t)(n0 + rn) * K + k0 + c8) = *(const uint4*)tmp;
  }
}

// ---- merged preprocessing: Wqkv transpose tiles FIRST (long pole), then
//      hidden->bf16 conv blocks (short, backfill the tail) ------------------
__global__ __launch_bounds__(256) void prep_kernel(
    const float* __restrict__ hidden, u16* __restrict__ A1,
    const float* __restrict__ Wqkv, u16* __restrict__ Wt)
{
  __shared__ u16 tile[64][72];
  const int bid = blockIdx.x, t = threadIdx.x;
  if (bid < 5254) {                       // 74 x 71 transpose tiles first
    int n0 = (bid % 74) * 64, k0 = (bid / 74) * 64;
    transpose_tile<256>(Wqkv, Wt, 4544, 4672, n0, k0, t, tile);
  } else {                                // conv: 4544*256*8 == 2048*4544 exact
    int i = (bid - 5254) * 256 + t;
    float4 a = *(const float4*)(hidden + (size_t)i * 8);
    float4 b = *(const float4*)(hidden + (size_t)i * 8 + 4);
    __align__(16) u16 tmp[8] = {f2b(a.x), f2b(a.y), f2b(a.z), f2b(a.w),
                                f2b(b.x), f2b(b.y), f2b(b.z), f2b(b.w)};
    *(uint4*)(A1 + (size_t)i * 8) = *(const uint4*)tmp;
  }
}

// ---- GEMM: C[M,N] = A[M,K] * B^T  (A bf16 [M][K], B bf16 [Npad][K]) --------
// r10 proven config: 128x128, 4 waves, BK=32, double-buffered 32 KB LDS,
// depth-1.5 pipeline: STAGE(t+1) -> vmcnt(4) -> barrier -> ds_read+MFMA ->
// barrier. Counted wait never drains in-loop. 64B-row XOR swizzle both-sides.
// MODE 0: plain fp32 C store. MODE 2: fused RoPE/QKV-split epilogue.
template<int MODE>
__global__ __launch_bounds__(256) void gemm_bt(
    const u16* __restrict__ A, const u16* __restrict__ B,
    float* __restrict__ Cptr,
    u16* __restrict__ qo, u16* __restrict__ ko, u16* __restrict__ vo,
    const int* __restrict__ pos,
    int M, int N, int K, int NBX)
{
  __shared__ __align__(16) u16 aLds[2][128 * 32];
  __shared__ __align__(16) u16 bLds[2][128 * 32];

  const int t = threadIdx.x, lane = t & 63, w = t >> 6;
  const int lr = lane & 15, lg = lane >> 4;
  const int wr = w >> 1, wc = w & 1;

  const int bid = blockIdx.x;
  const int qq  = gridDim.x >> 3;
  const int swz = (bid & 7) * qq + (bid >> 3);    // bijective: grid % 8 == 0
  const int m0 = (swz / NBX) * 128, n0 = (swz % NBX) * 128;

  const int srow = lane >> 2;                        // 0..15
  const int ssl  = ((lane & 3) ^ ((lane >> 3) & 3)) << 3;  // swizzled src col (u16)

  f32x4 acc[4][4] = {};
  const int nk = K >> 5;                 // 4544/32 = 142

#define STAGE(buf, tt) do {                                                   \
    size_t kq_ = (size_t)(tt) << 5;                                           \
    _Pragma("unroll")                                                         \
    for (int i_ = 0; i_ < 2; ++i_) {                                          \
      int row_ = i_ * 64 + w * 16 + srow;                                     \
      gload16(A + (size_t)(m0 + row_) * K + kq_ + ssl,                        \
              (char*)&aLds[buf][0] + i_ * 4096 + w * 1024);                   \
      gload16(B + (size_t)(n0 + row_) * K + kq_ + ssl,                        \
              (char*)&bLds[buf][0] + i_ * 4096 + w * 1024);                   \
    }                                                                         \
  } while (0)

  // prologue: tile 0 in flight
  STAGE(0, 0);

  const int sl = (lg ^ ((lr >> 1) & 3)) << 3;        // swizzled read slot (u16)
  for (int kt = 0; kt < nk; ++kt) {
    const int cur = kt & 1;
    if (kt + 1 < nk) {
      STAGE(cur ^ 1, kt + 1);                         // issue early (pre-wait)
      asm volatile("s_waitcnt vmcnt(4)" ::: "memory");   // tile kt landed
    } else {
      asm volatile("s_waitcnt vmcnt(0)" ::: "memory");
    }
    __builtin_amdgcn_s_barrier();          // all waves' tile-kt loads landed
    __builtin_amdgcn_sched_barrier(0);     // pin: no ds_read above barrier
    const u16* ab = &aLds[cur][0];
    const u16* bb = &bLds[cur][0];
    s16x8 af[4], bf[4];
    #pragma unroll
    for (int m = 0; m < 4; ++m)
      af[m] = *(const s16x8*)(ab + (wr * 64 + m * 16 + lr) * 32 + sl);
    #pragma unroll
    for (int n = 0; n < 4; ++n)
      bf[n] = *(const s16x8*)(bb + (wc * 64 + n * 16 + lr) * 32 + sl);
    #pragma unroll
    for (int m = 0; m < 4; ++m)
      #pragma unroll
      for (int n = 0; n < 4; ++n)
        acc[m][n] = __builtin_amdgcn_mfma_f32_16x16x32_bf16(af[m], bf[n], acc[m][n], 0, 0, 0);
    __builtin_amdgcn_s_barrier();          // reads(kt) done before STAGE(kt+2)
  }
#undef STAGE

  if constexpr (MODE == 0) {
    #pragma unroll
    for (int m = 0; m < 4; ++m) {
      int row = m0 + wr * 64 + m * 16 + lg * 4;
      #pragma unroll
      for (int n = 0; n < 4; ++n) {
        int col = n0 + wc * 64 + n * 16 + lr;
        if (col < N) {
          #pragma unroll
          for (int r = 0; r < 4; ++r)
            Cptr[(size_t)(row + r) * N + col] = acc[m][n][r];
        }
      }
    }
  } else {
    const int h = (n0 + wc * 64) >> 6;       // head index for this wave
    if (h > 72) return;                       // zero-padded columns
    const float inv0 = exp2f(-0.41524101186092029f * (float)lr);
    const float inv1 = exp2f(-0.41524101186092029f * (float)(16 + lr));
    #pragma unroll
    for (int m = 0; m < 4; ++m) {
      #pragma unroll
      for (int r = 0; r < 4; ++r) {
        int row = m0 + wr * 64 + m * 16 + lg * 4 + r;
        int b = row >> 10, s = row & 1023;
        if (h == 72) {                        // V: no rope, transposed store
          #pragma unroll
          for (int n = 0; n < 4; ++n) {
            int d = n * 16 + lr;
            vo[((size_t)b * 64 + d) * 1024 + s] = f2b(acc[m][n][r]);
          }
        } else {                              // Q / K: rope in registers
          float p = (float)pos[s];
          float sn0, cs0, sn1, cs1;
          __sincosf(p * inv0, &sn0, &cs0);
          __sincosf(p * inv1, &sn1, &cs1);
          #pragma unroll
          for (int n = 0; n < 4; ++n) {
            float cs  = (n & 1) ? cs1 : cs0;
            float sn  = (n & 1) ? sn1 : sn0;
            float sgn = (n < 2) ? -1.f : 1.f;
            float val = acc[m][n][r] * cs + sgn * acc[m][n ^ 2][r] * sn;
            int d = n * 16 + lr;
            if (h < 71)
              qo[((size_t)(b * 71 + h) * 1024 + s) * 64 + d] = f2b(val);
            else
              ko[((size_t)b * 1024 + s) * 64 + d] = f2b(val);
          }
        }
      }
    }
  }
}

// ---- attention (blocks 0..2271) + Wdense transpose (blocks 2272..) ---------
// attn: swapped-QK 32x32 MFMA, in-reg softmax, no LDS/barriers; 2 waves/block.
// T15 double-pipeline: QK(it+1) overlaps softmax(it). kf regs are reused for a
// 2-iteration K prefetch (zero extra state); QK writes back into sa/sb after
// the s[]-extraction kills them (kZero as first-MFMA C-in).
__global__ __launch_bounds__(128) void attn_plus(
    const u16* __restrict__ q, const u16* __restrict__ kx,
    const u16* __restrict__ vT, u16* __restrict__ attnO,
    const float* __restrict__ Wd, u16* __restrict__ Wt)
{
  __shared__ u16 tile[64][72];
  const int bid = blockIdx.x;
  if (bid >= 2272) {                        // 72 x 71 transpose tiles
    int tb = bid - 2272;
    int n0 = (tb % 72) * 64, k0 = (tb / 72) * 64;
    transpose_tile<128>(Wd, Wt, 4544, 4544, n0, k0, threadIdx.x, tile);
    return;
  }
  const int t = threadIdx.x, lane = t & 63, w = t >> 6;
  const int lq  = lane & 31;
  const int hi  = lane >> 5;
  const int hi4 = hi << 2;
  const int pair = bid & 15, h = (bid >> 4) % 71, b = bid / 1136;
  const int qt = w ? (31 - pair) : pair;
  const int q0 = qt * 32;

  const u16* qbase = q + ((size_t)(b * 71 + h) * 1024 + q0 + lq) * 64 + hi * 8;
  s16x8 qf[4];
  #pragma unroll
  for (int kt = 0; kt < 4; ++kt) qf[kt] = *(const s16x8*)(qbase + kt * 16);

  f32x16 o0 = {}, o1 = {};
  float m = -1e30f, l = 0.f;

  const u16* kbase  = kx + ((size_t)b * 1024 + lq) * 64 + hi * 8;
  const u16* vbase0 = vT + ((size_t)b * 64 + lq) * 1024 + hi * 8;
  const u16* vbase1 = vbase0 + 32 * 1024;

  const f32x16 kZero = {};

  // prologue: QK(0); then prefetch K(1) into the freed kf regs
  s16x8 kf[4];
  #pragma unroll
  for (int kt = 0; kt < 4; ++kt)
    kf[kt] = *(const s16x8*)(kbase + kt * 16);
  f32x16 sa, sb;
  sa = __builtin_amdgcn_mfma_f32_32x32x16_bf16(kf[0], qf[0], kZero, 0, 0, 0);
  sb = __builtin_amdgcn_mfma_f32_32x32x16_bf16(kf[1], qf[1], kZero, 0, 0, 0);
  sa = __builtin_amdgcn_mfma_f32_32x32x16_bf16(kf[2], qf[2], sa, 0, 0, 0);
  sb = __builtin_amdgcn_mfma_f32_32x32x16_bf16(kf[3], qf[3], sb, 0, 0, 0);
  if (qt >= 1) {
    #pragma unroll
    for (int kt = 0; kt < 4; ++kt)
      kf[kt] = *(const s16x8*)(kbase + (size_t)32 * 64 + kt * 16);
  }

  for (int it = 0; it <= qt; ++it) {
    const int kv0 = it * 32;
    // V(it) loads (used at PV, latency covered by softmax+QK)
    s16x8 v00 = *(const s16x8*)(vbase0 + kv0);
    s16x8 v01 = *(const s16x8*)(vbase0 + kv0 + 16);
    s16x8 v10 = *(const s16x8*)(vbase1 + kv0);
    s16x8 v11 = *(const s16x8*)(vbase1 + kv0 + 16);

    // ---- s[] extraction: consumes sa/sb (they are dead afterwards) ----
    float s[16];
    float pmax = -1e30f;
    if (it == qt) {
      #pragma unroll
      for (int r = 0; r < 16; ++r) {
        int R = (r & 3) + ((r >> 2) << 3) + hi4;
        s[r] = (R > lq) ? -1e30f : (sa[r] + sb[r]) * 0.125f;
        pmax = fmaxf(pmax, s[r]);
      }
    } else {
      #pragma unroll
      for (int r = 0; r < 16; ++r) {
        s[r] = (sa[r] + sb[r]) * 0.125f;
        pmax = fmaxf(pmax, s[r]);
      }
    }

    // ---- QK(it+1) into sa/sb (MFMA pipe busy while softmax VALU runs) ----
    if (it < qt) {
      sa = __builtin_amdgcn_mfma_f32_32x32x16_bf16(kf[0], qf[0], kZero, 0, 0, 0);
      sb = __builtin_amdgcn_mfma_f32_32x32x16_bf16(kf[1], qf[1], kZero, 0, 0, 0);
      sa = __builtin_amdgcn_mfma_f32_32x32x16_bf16(kf[2], qf[2], sa, 0, 0, 0);
      sb = __builtin_amdgcn_mfma_f32_32x32x16_bf16(kf[3], qf[3], sb, 0, 0, 0);
    }
    // ---- prefetch K(it+2) into the just-freed kf regs ----
    if (it + 2 <= qt) {
      #pragma unroll
      for (int kt = 0; kt < 4; ++kt)
        kf[kt] = *(const s16x8*)(kbase + (size_t)(kv0 + 64) * 64 + kt * 16);
    }

    // ---- rest of softmax (VALU; overlaps QK(it+1) execution) ----
    pmax = fmaxf(pmax, __shfl_xor(pmax, 32));
    if (!__all(pmax <= m + 8.f)) {
      float mn = fmaxf(m, pmax);
      float corr = __expf(m - mn);
      m = mn;
      l *= corr;
      #pragma unroll
      for (int r = 0; r < 16; ++r) {
        float c2 = __shfl(corr, (r & 3) + ((r >> 2) << 3) + hi4);
        o0[r] *= c2; o1[r] *= c2;
      }
    }
    float p[16], sum = 0.f;
    #pragma unroll
    for (int r = 0; r < 16; ++r) { p[r] = __expf(s[r] - m); sum += p[r]; }
    sum += __shfl_xor(sum, 32);
    l += sum;

    unsigned int a0 = cvtpk(p[0], p[1]),   a1 = cvtpk(p[2], p[3]);
    unsigned int b0 = cvtpk(p[4], p[5]),   b1 = cvtpk(p[6], p[7]);
    asm("v_permlane32_swap_b32 %0, %1" : "+v"(a0), "+v"(b0));
    asm("v_permlane32_swap_b32 %0, %1" : "+v"(a1), "+v"(b1));
    unsigned int c0 = cvtpk(p[8], p[9]),   c1 = cvtpk(p[10], p[11]);
    unsigned int d0 = cvtpk(p[12], p[13]), d1 = cvtpk(p[14], p[15]);
    asm("v_permlane32_swap_b32 %0, %1" : "+v"(c0), "+v"(d0));
    asm("v_permlane32_swap_b32 %0, %1" : "+v"(c1), "+v"(d1));
    union { unsigned int wd[4]; s16x8 v; } palo, pahi;
    palo.wd[0] = a0; palo.wd[1] = a1; palo.wd[2] = b0; palo.wd[3] = b1;
    pahi.wd[0] = c0; pahi.wd[1] = c1; pahi.wd[2] = d0; pahi.wd[3] = d1;

    // ---- PV(it) ----
    o0 = __builtin_amdgcn_mfma_f32_32x32x16_bf16(palo.v, v00, o0, 0, 0, 0);
    o0 = __builtin_amdgcn_mfma_f32_32x32x16_bf16(pahi.v, v01, o0, 0, 0, 0);
    o1 = __builtin_amdgcn_mfma_f32_32x32x16_bf16(palo.v, v10, o1, 0, 0, 0);
    o1 = __builtin_amdgcn_mfma_f32_32x32x16_bf16(pahi.v, v11, o1, 0, 0, 0);
  }

  float linv = 1.f / l;
  #pragma unroll
  for (int r = 0; r < 16; ++r) {
    int R = (r & 3) + ((r >> 2) << 3) + hi4;
    float c2 = __shfl(linv, R);
    size_t base = ((size_t)(b * 1024 + q0 + R) * 71 + h) * 64;
    attnO[base + lq]      = f2b(o0[r] * c2);
    attnO[base + 32 + lq] = f2b(o1[r] * c2);
  }
}

// ---- launcher --------------------------------------------------------------
extern "C" void kernel_launch(void* const* d_in, const int* in_sizes, int n_in,
                              void* d_out, int out_size, void* d_ws, size_t ws_size,
                              hipStream_t stream) {
  const float* hidden = (const float*)d_in[0];   // [2,1024,4544]
  const float* Wqkv   = (const float*)d_in[1];   // [4544,4672]
  const float* Wdense = (const float*)d_in[2];   // [4544,4544]
  const int*   pos    = (const int*)d_in[4];     // [1,1024]
  float* out = (float*)d_out;                    // [2,1024,4544] fp32

  char* wsp = (char*)d_ws;
  // buffer plan (82.0 MB total):
  //  Wt:   4736 x 4544 bf16 = 43,040,768   (Wqkv^T, then overwritten by Wdense^T)
  //  A1:   18,612,224  hidden bf16 -> (after GEMM1) reused as attn output
  //  q:    18,612,224
  //  k,vT: 262,144 each
  u16* Wt    = (u16*)(wsp);
  u16* A1    = (u16*)(wsp + 43040768);
  u16* qws   = (u16*)(wsp + 43040768 + 18612224);
  u16* kws   = (u16*)(wsp + 43040768 + 18612224 + 18612224);
  u16* vws   = (u16*)(wsp + 43040768 + 18612224 + 18612224 + 262144);
  u16* attnw = A1;     // A1 dead after GEMM1 reads it

  // 1) merged: Wqkv^T->bf16 (5254 blocks, first) + hidden->bf16 (4544 blocks)
  prep_kernel<<<5254 + 4544, 256, 0, stream>>>(hidden, A1, Wqkv, Wt);
  // 2) QKV GEMM (M=2048, Npad=4736, K=4544): 592 blocks (128x128, r10 config)
  gemm_bt<2><<<592, 256, 0, stream>>>(A1, Wt, nullptr, qws, kws, vws, pos,
                                      2048, 4672, 4544, 37);
  // 3) merged: attention (2272) + Wdense^T->bf16 (5112)
  attn_plus<<<2272 + 5112, 128, 0, stream>>>(qws, kws, vws, attnw, Wdense, Wt);
  // 4) out = attn @ W_dense (M=2048, Npad=4608, K=4544): 576 blocks
  gemm_bt<0><<<576, 256, 0, stream>>>(attnw, Wt, out, nullptr, nullptr, nullptr,
                                      nullptr, 2048, 4544, 4544, 36);
}